// Round 1
// baseline (691.913 us; speedup 1.0000x reference)
//
#include <hip/hip_runtime.h>
#include <hip/hip_bf16.h>
#include <math.h>

// Problem constants (fixed-shape problem)
#define N_NODES 50000
#define FIN     32
#define HID     64
#define HC      128     // HEADS*HID
#define NE      800000
#define NET     850000  // NE + N self loops
#define NI      10000   // interface nodes
#define NG      50      // graphs

#define SCAN_CHUNK 1024
#define SCAN_NB ((N_NODES + SCAN_CHUNK - 1) / SCAN_CHUNK)  // 49

__device__ __forceinline__ float lrelu(float x) { return x > 0.f ? x : 0.2f * x; }

// order-preserving float->uint encoding for atomicMax; 0 == "less than any float"
__device__ __forceinline__ unsigned fenc(float f) {
  unsigned u = __float_as_uint(f);
  return (u & 0x80000000u) ? ~u : (u | 0x80000000u);
}
__device__ __forceinline__ float fdec(unsigned u) {
  return (u & 0x80000000u) ? __uint_as_float(u ^ 0x80000000u) : __uint_as_float(~u);
}

__device__ __forceinline__ float rlf(float v, int l) {
  return __int_as_float(__builtin_amdgcn_readlane(__float_as_int(v), l));
}
__device__ __forceinline__ int rli(int v, int l) {
  return __builtin_amdgcn_readlane(v, l);
}

// ---------------- CSR build ----------------
__global__ void k_hist(const int* __restrict__ ei, int* __restrict__ deg) {
  int e = blockIdx.x * blockDim.x + threadIdx.x;
  if (e >= NET) return;
  int d = (e < NE) ? ei[NE + e] : (e - NE);
  atomicAdd(&deg[d], 1);
}

__global__ void k_scan_a(const int* __restrict__ deg, int* __restrict__ bsum) {
  __shared__ int red[256];
  int b = blockIdx.x, t = threadIdx.x;
  int s = 0;
  for (int k = 0; k < 4; k++) {
    int i = b * SCAN_CHUNK + k * 256 + t;
    if (i < N_NODES) s += deg[i];
  }
  red[t] = s; __syncthreads();
  for (int off = 128; off; off >>= 1) { if (t < off) red[t] += red[t + off]; __syncthreads(); }
  if (t == 0) bsum[b] = red[0];
}

__global__ void k_scan_b(const int* __restrict__ bsum, int* __restrict__ bscan) {
  if (threadIdx.x == 0) {
    int c = 0;
    for (int i = 0; i < SCAN_NB; i++) { bscan[i] = c; c += bsum[i]; }
  }
}

__global__ void k_scan_c(const int* __restrict__ deg, const int* __restrict__ bscan,
                         int* __restrict__ offs) {
  __shared__ int buf[SCAN_CHUNK];
  int b = blockIdx.x, t = threadIdx.x;  // 1024 threads
  int i = b * SCAN_CHUNK + t;
  int v = (i < N_NODES) ? deg[i] : 0;
  buf[t] = v; __syncthreads();
  for (int off = 1; off < SCAN_CHUNK; off <<= 1) {
    int a = (t >= off) ? buf[t - off] : 0;
    __syncthreads();
    buf[t] += a;
    __syncthreads();
  }
  int excl = bscan[b] + buf[t] - v;
  if (i < N_NODES) offs[i] = excl;
  if (i == N_NODES - 1) offs[N_NODES] = excl + v;
}

__global__ void k_scatter(const int* __restrict__ ei, const float* __restrict__ eattr,
                          const int* __restrict__ offs, int* __restrict__ cursor,
                          int* __restrict__ bsrc, float2* __restrict__ bea) {
  int e = blockIdx.x * blockDim.x + threadIdx.x;
  if (e >= NET) return;
  int s, d; float ex, ey;
  if (e < NE) {
    s = ei[e]; d = ei[NE + e];
    ex = 1.0f / eattr[2 * e]; ey = 1.0f / eattr[2 * e + 1];
  } else {
    s = d = e - NE; ex = 0.f; ey = 0.f;
  }
  int pos = offs[d] + atomicAdd(&cursor[d], 1);
  bsrc[pos] = s;
  bea[pos] = make_float2(ex, ey);
}

// ---------------- per-layer node linear + attention dots ----------------
// block = 128 threads (thread = output channel c = head*64+cc). W column kept in
// registers; h rows read as wave-uniform float4 broadcasts (1 VMEM / 4 FMA-inst).
// xl stored head-interleaved: xl2[n*128 + cc*2 + head] so aggregate reads float2.
template <int F>
__global__ void k_linear(const float* __restrict__ h, const float* __restrict__ W,
                         const float* __restrict__ attl, const float* __restrict__ attr,
                         float* __restrict__ xl2, float* __restrict__ al, float* __restrict__ ar) {
  const int c = threadIdx.x;
  const int head = c >> 6;
  const int cc = c & 63;
  float wcol[F];
#pragma unroll
  for (int k = 0; k < F; k++) wcol[k] = W[k * HC + c];
  const float attlv = attl[c];
  const float attrv = attr[c];
  for (int g = blockIdx.x; g < N_NODES / 4; g += gridDim.x) {
    const int n0 = g * 4;
    float acc[4] = {0.f, 0.f, 0.f, 0.f};
#pragma unroll
    for (int k4 = 0; k4 < F / 4; k4++) {
      float4 h4[4];
#pragma unroll
      for (int j = 0; j < 4; j++)
        h4[j] = *(const float4*)&h[(n0 + j) * F + k4 * 4];
#pragma unroll
      for (int j = 0; j < 4; j++) {
        acc[j] += h4[j].x * wcol[k4 * 4 + 0];
        acc[j] += h4[j].y * wcol[k4 * 4 + 1];
        acc[j] += h4[j].z * wcol[k4 * 4 + 2];
        acc[j] += h4[j].w * wcol[k4 * 4 + 3];
      }
    }
#pragma unroll
    for (int j = 0; j < 4; j++) {
      xl2[(n0 + j) * HC + cc * 2 + head] = acc[j];
      float lv = acc[j] * attlv, rv = acc[j] * attrv;
#pragma unroll
      for (int off = 32; off; off >>= 1) {
        lv += __shfl_xor(lv, off, 64);
        rv += __shfl_xor(rv, off, 64);
      }
      if (cc == 0) {
        al[(n0 + j) * 2 + head] = lv;
        ar[(n0 + j) * 2 + head] = rv;
      }
    }
  }
}

// ---------------- per-layer edge aggregation ----------------
// 1 wave per dst node; 4 waves per 256-thread block. Softmax scores computed
// strip-parallel (<=64 edges per strip); serial edge loop is just
// 3 readlanes + 1 coalesced float2 load + 2 FMA. The ee (edge-embedding) term
// is folded into per-head scalars: sum_p, sum_p*ea.x, sum_p*ea.y.
__global__ void k_aggregate(const float* __restrict__ xl2, const float* __restrict__ al,
                            const float* __restrict__ ar, const int* __restrict__ offs,
                            const int* __restrict__ bsrc, const float2* __restrict__ bea,
                            const float* __restrict__ eW2, const float* __restrict__ eb1,
                            const float* __restrict__ bconv1, float* __restrict__ hout,
                            float* __restrict__ xmax, int first) {
  const int gid = blockIdx.x * 4 + (threadIdx.x >> 6);
  if (gid >= N_NODES) return;
  const int lane = threadIdx.x & 63;
  const int o0 = offs[gid];
  const int deg = offs[gid + 1] - o0;
  const float2 arv = ((const float2*)ar)[gid];

  // phase 1: per-head max over incoming edges (strip-parallel)
  float lm0 = -1e30f, lm1 = -1e30f;
  for (int base = 0; base < deg; base += 64) {
    int j = base + lane;
    if (j < deg) {
      int s = bsrc[o0 + j];
      float2 alv = ((const float2*)al)[s];
      lm0 = fmaxf(lm0, lrelu(alv.x + arv.x));
      lm1 = fmaxf(lm1, lrelu(alv.y + arv.y));
    }
  }
#pragma unroll
  for (int off = 32; off; off >>= 1) {
    lm0 = fmaxf(lm0, __shfl_xor(lm0, off, 64));
    lm1 = fmaxf(lm1, __shfl_xor(lm1, off, 64));
  }

  // phase 2: weighted accumulation
  float acc0 = 0.f, acc1 = 0.f;
  float ld0 = 0.f, ld1 = 0.f, lex0 = 0.f, ley0 = 0.f, lex1 = 0.f, ley1 = 0.f;
  for (int base = 0; base < deg; base += 64) {
    int j = base + lane;
    int s = 0; float p0 = 0.f, p1 = 0.f;
    if (j < deg) {
      s = bsrc[o0 + j];
      float2 eav = bea[o0 + j];
      float2 alv = ((const float2*)al)[s];
      p0 = __expf(lrelu(alv.x + arv.x) - lm0);
      p1 = __expf(lrelu(alv.y + arv.y) - lm1);
      ld0 += p0; ld1 += p1;
      lex0 += p0 * eav.x; ley0 += p0 * eav.y;
      lex1 += p1 * eav.x; ley1 += p1 * eav.y;
    }
    int slen = min(64, deg - base);
    for (int j2 = 0; j2 < slen; j2++) {
      int   sj  = rli(s, j2);
      float p0j = rlf(p0, j2);
      float p1j = rlf(p1, j2);
      float2 xv = ((const float2*)xl2)[sj * 64 + lane];
      acc0 += p0j * xv.x;
      acc1 += p1j * xv.y;
    }
  }
#pragma unroll
  for (int off = 32; off; off >>= 1) {
    ld0  += __shfl_xor(ld0, off, 64);
    ld1  += __shfl_xor(ld1, off, 64);
    lex0 += __shfl_xor(lex0, off, 64);
    ley0 += __shfl_xor(ley0, off, 64);
    lex1 += __shfl_xor(lex1, off, 64);
    ley1 += __shfl_xor(ley1, off, 64);
  }
  // fold edge-embedding contribution: sum_j p_j*(eW@ea_j + eb)
  float t0 = acc0 + eW2[lane]      * lex0 + eW2[HC + lane]      * ley0 + eb1[lane]      * ld0;
  float t1 = acc1 + eW2[64 + lane] * lex1 + eW2[HC + 64 + lane] * ley1 + eb1[64 + lane] * ld1;
  float r = 0.5f * (t0 / (ld0 + 1e-16f) + t1 / (ld1 + 1e-16f)) + bconv1[lane];
  float hv = tanhf(r);
  hout[gid * HID + lane] = hv;
  xmax[gid * HID + lane] = first ? hv : fmaxf(xmax[gid * HID + lane], hv);
}

// ---------------- pooling ----------------
__global__ void k_pool1(const float* __restrict__ xmax, const int* __restrict__ ipos,
                        const int* __restrict__ batch, const float* __restrict__ gate_w,
                        const float* __restrict__ gate_b, float* __restrict__ add,
                        unsigned* __restrict__ mxE, float* __restrict__ cnt,
                        float* __restrict__ gate, unsigned* __restrict__ gmaxE) {
  int i = blockIdx.x * 4 + (threadIdx.x >> 6);
  if (i >= NI) return;
  int lane = threadIdx.x & 63;
  int node = ipos[i];
  int g = batch[node];
  float v = xmax[node * HID + lane];
  atomicAdd(&add[g * HID + lane], v);
  atomicMax(&mxE[g * HID + lane], fenc(v));
  float gv = v * gate_w[lane];
#pragma unroll
  for (int off = 32; off; off >>= 1) gv += __shfl_xor(gv, off, 64);
  if (lane == 0) {
    float gs = gv + gate_b[0];
    gate[i] = gs;
    atomicMax(&gmaxE[g], fenc(gs));
    atomicAdd(&cnt[g], 1.f);
  }
}

__global__ void k_pool2(const float* __restrict__ xmax, const int* __restrict__ ipos,
                        const int* __restrict__ batch, const float* __restrict__ gate,
                        const unsigned* __restrict__ gmaxE, float* __restrict__ attp,
                        float* __restrict__ aden) {
  int i = blockIdx.x * 4 + (threadIdx.x >> 6);
  if (i >= NI) return;
  int lane = threadIdx.x & 63;
  int node = ipos[i];
  int g = batch[node];
  float a = __expf(gate[i] - fdec(gmaxE[g]));
  float v = xmax[node * HID + lane];
  atomicAdd(&attp[g * HID + lane], a * v);
  if (lane == 0) atomicAdd(&aden[g], a);
}

__global__ void k_final(const float* __restrict__ add, const float* __restrict__ cnt,
                        const float* __restrict__ attp, const float* __restrict__ aden,
                        const unsigned* __restrict__ mxE, const float* __restrict__ lin1_w,
                        const float* __restrict__ lin1_b, const float* __restrict__ lin2_w,
                        const float* __restrict__ lin2_b, float* __restrict__ out) {
  __shared__ float pooled[4 * HID];
  __shared__ float zred[2 * HID];
  int g = blockIdx.x, t = threadIdx.x;  // 256 threads
  if (t < HID)            pooled[t] = add[g * HID + t];
  else if (t < 2 * HID)   pooled[t] = add[g * HID + (t - HID)] / fmaxf(cnt[g], 1.f);
  else if (t < 3 * HID)   pooled[t] = attp[g * HID + (t - 2 * HID)] / (aden[g] + 1e-16f);
  else                    pooled[t] = fdec(mxE[g * HID + (t - 3 * HID)]);
  __syncthreads();
  if (t < 2 * HID) {
    float z = lin1_b[t];
    for (int k = 0; k < 4 * HID; k++) z += pooled[k] * lin1_w[k * (2 * HID) + t];
    z = tanhf(z);
    zred[t] = z * lin2_w[t];
  }
  __syncthreads();
  if (t == 0) {
    float s = 0.f;
    for (int k = 0; k < 2 * HID; k++) s += zred[k];
    out[g] = s + lin2_b[0];
  }
}

extern "C" void kernel_launch(void* const* d_in, const int* in_sizes, int n_in,
                              void* d_out, int out_size, void* d_ws, size_t ws_size,
                              hipStream_t stream) {
  const float* x      = (const float*)d_in[0];
  const int*   ei     = (const int*)d_in[1];
  const float* eattr  = (const float*)d_in[2];
  const int*   batch  = (const int*)d_in[3];
  const int*   ipos   = (const int*)d_in[4];
  // d_in[5] = graph_num scalar (G=50, hardcoded)
  const float* W0     = (const float*)d_in[6];
  const float* attl0  = (const float*)d_in[7];
  const float* attr0  = (const float*)d_in[8];
  const float* W12    = (const float*)d_in[9];
  const float* attl12 = (const float*)d_in[10];
  const float* attr12 = (const float*)d_in[11];
  const float* eW     = (const float*)d_in[12];
  const float* eb     = (const float*)d_in[13];
  const float* bconv  = (const float*)d_in[14];
  const float* gate_w = (const float*)d_in[15];
  const float* gate_b = (const float*)d_in[16];
  const float* lin1_w = (const float*)d_in[17];
  const float* lin1_b = (const float*)d_in[18];
  const float* lin2_w = (const float*)d_in[19];
  const float* lin2_b = (const float*)d_in[20];
  float* out = (float*)d_out;

  char* ws = (char*)d_ws;
  size_t off = 0;
  auto alloc = [&](size_t elems) { void* p = ws + off; off += elems * 4; return p; };
  // ---- zero-init region (contiguous, one memset) ----
  int*      deg    = (int*)alloc(N_NODES);
  int*      cursor = (int*)alloc(N_NODES);
  float*    addp   = (float*)alloc(NG * HID);
  float*    attp   = (float*)alloc(NG * HID);
  unsigned* mxE    = (unsigned*)alloc(NG * HID);
  float*    cnt    = (float*)alloc(64);
  unsigned* gmaxE  = (unsigned*)alloc(64);
  float*    aden   = (float*)alloc(64);
  size_t zbytes = off;
  // ---- rest ----
  int*   offs  = (int*)alloc(N_NODES + 4);
  int*   bsum  = (int*)alloc(64);
  int*   bscan = (int*)alloc(64);
  int*   bsrc  = (int*)alloc(NET);
  float* beaf  = (float*)alloc((size_t)NET * 2);
  float* xl2   = (float*)alloc((size_t)N_NODES * HC);
  float* al    = (float*)alloc(N_NODES * 2);
  float* arr   = (float*)alloc(N_NODES * 2);
  float* hbuf  = (float*)alloc((size_t)N_NODES * HID);
  float* xmax  = (float*)alloc((size_t)N_NODES * HID);
  float* gate  = (float*)alloc(NI);
  (void)ws_size; (void)in_sizes; (void)n_in; (void)out_size;

  hipMemsetAsync(d_ws, 0, zbytes, stream);
  k_hist<<<(NET + 255) / 256, 256, 0, stream>>>(ei, deg);
  k_scan_a<<<SCAN_NB, 256, 0, stream>>>(deg, bsum);
  k_scan_b<<<1, 64, 0, stream>>>(bsum, bscan);
  k_scan_c<<<SCAN_NB, 1024, 0, stream>>>(deg, bscan, offs);
  k_scatter<<<(NET + 255) / 256, 256, 0, stream>>>(ei, eattr, offs, cursor, bsrc, (float2*)beaf);

  // layer 0
  k_linear<FIN><<<2500, 128, 0, stream>>>(x, W0, attl0, attr0, xl2, al, arr);
  k_aggregate<<<N_NODES / 4, 256, 0, stream>>>(xl2, al, arr, offs, bsrc, (const float2*)beaf,
                                               eW, eb, bconv, hbuf, xmax, 1);
  // layers 1,2
  for (int l = 0; l < 2; l++) {
    k_linear<HID><<<2500, 128, 0, stream>>>(hbuf, W12 + (size_t)l * HID * HC,
                                            attl12 + l * HC, attr12 + l * HC, xl2, al, arr);
    k_aggregate<<<N_NODES / 4, 256, 0, stream>>>(xl2, al, arr, offs, bsrc, (const float2*)beaf,
                                                 eW + (l + 1) * 2 * HC, eb + (l + 1) * HC,
                                                 bconv + (l + 1) * HID, hbuf, xmax, 0);
  }

  k_pool1<<<NI / 4, 256, 0, stream>>>(xmax, ipos, batch, gate_w, gate_b, addp, mxE, cnt, gate, gmaxE);
  k_pool2<<<NI / 4, 256, 0, stream>>>(xmax, ipos, batch, gate, gmaxE, attp, aden);
  k_final<<<NG, 256, 0, stream>>>(addp, cnt, attp, aden, mxE, lin1_w, lin1_b, lin2_w, lin2_b, out);
}

// Round 2
// 490.718 us; speedup vs baseline: 1.4100x; 1.4100x over previous
//
#include <hip/hip_runtime.h>
#include <hip/hip_bf16.h>
#include <hip/hip_fp16.h>
#include <math.h>

// Problem constants (fixed-shape problem)
#define N_NODES 50000
#define FIN     32
#define HID     64
#define HC      128     // HEADS*HID
#define NE      800000
#define NET     850000  // NE + N self loops
#define NI      10000   // interface nodes
#define NG      50      // graphs

__device__ __forceinline__ float lrelu(float x) { return x > 0.f ? x : 0.2f * x; }

__device__ __forceinline__ float rlf(float v, int l) {
  return __int_as_float(__builtin_amdgcn_readlane(__float_as_int(v), l));
}
__device__ __forceinline__ int rli(int v, int l) {
  return __builtin_amdgcn_readlane(v, l);
}

// ---------------- CSR build (unordered buckets) ----------------
__global__ void k_hist(const int* __restrict__ ei, int* __restrict__ deg) {
  int e = blockIdx.x * blockDim.x + threadIdx.x;
  if (e >= NET) return;
  int d = (e < NE) ? ei[NE + e] : (e - NE);
  atomicAdd(&deg[d], 1);
}

// block-scan + one global atomic per block for the base; bucket ranges are
// disjoint but NOT sorted by node id — aggregate only needs [start, start+deg).
__global__ void k_base(const int* __restrict__ deg, int* __restrict__ start,
                       int* __restrict__ gcur) {
  __shared__ int buf[256];
  __shared__ int basesh;
  int t = threadIdx.x;
  int i = blockIdx.x * 256 + t;
  int v = (i < N_NODES) ? deg[i] : 0;
  buf[t] = v; __syncthreads();
  for (int off = 1; off < 256; off <<= 1) {
    int a = (t >= off) ? buf[t - off] : 0;
    __syncthreads();
    buf[t] += a;
    __syncthreads();
  }
  if (t == 255) basesh = atomicAdd(gcur, buf[255]);
  __syncthreads();
  if (i < N_NODES) start[i] = basesh + buf[t] - v;
}

// edge record: {src(int bits), 1/ea.x, 1/ea.y, 0} — one 16B store / load
__global__ void k_scatter(const int* __restrict__ ei, const float* __restrict__ eattr,
                          const int* __restrict__ start, int* __restrict__ cursor,
                          float4* __restrict__ erec) {
  int e = blockIdx.x * blockDim.x + threadIdx.x;
  if (e >= NET) return;
  int s, d; float ex, ey;
  if (e < NE) {
    s = ei[e]; d = ei[NE + e];
    float2 ea = ((const float2*)eattr)[e];
    ex = 1.0f / ea.x; ey = 1.0f / ea.y;
  } else {
    s = d = e - NE; ex = 0.f; ey = 0.f;
  }
  int pos = start[d] + atomicAdd(&cursor[d], 1);
  erec[pos] = make_float4(__int_as_float(s), ex, ey, 0.f);
}

// ---------------- per-layer node linear + attention dots ----------------
// block = 128 threads (thread = output channel c = head*64+cc). W column kept in
// registers; h rows read as wave-uniform float4 broadcasts. xl written as packed
// __half2 (head-interleaved) via an LDS transpose: xl2h[n*64+cc] = (h0, h1).
template <int F>
__global__ void k_linear(const float* __restrict__ h, const float* __restrict__ W,
                         const float* __restrict__ attl, const float* __restrict__ attr,
                         __half2* __restrict__ xl2h, float* __restrict__ al,
                         float* __restrict__ ar) {
  __shared__ float lds[4][HC];
  const int c = threadIdx.x;
  const int head = c >> 6;
  const int cc = c & 63;
  float wcol[F];
#pragma unroll
  for (int k = 0; k < F; k++) wcol[k] = W[k * HC + c];
  const float attlv = attl[c];
  const float attrv = attr[c];
  for (int g = blockIdx.x; g < N_NODES / 4; g += gridDim.x) {
    const int n0 = g * 4;
    float acc[4] = {0.f, 0.f, 0.f, 0.f};
#pragma unroll
    for (int k4 = 0; k4 < F / 4; k4++) {
      float4 h4[4];
#pragma unroll
      for (int j = 0; j < 4; j++)
        h4[j] = *(const float4*)&h[(n0 + j) * F + k4 * 4];
#pragma unroll
      for (int j = 0; j < 4; j++) {
        acc[j] += h4[j].x * wcol[k4 * 4 + 0];
        acc[j] += h4[j].y * wcol[k4 * 4 + 1];
        acc[j] += h4[j].z * wcol[k4 * 4 + 2];
        acc[j] += h4[j].w * wcol[k4 * 4 + 3];
      }
    }
#pragma unroll
    for (int j = 0; j < 4; j++) {
      float lv = acc[j] * attlv, rv = acc[j] * attrv;
#pragma unroll
      for (int off = 32; off; off >>= 1) {
        lv += __shfl_xor(lv, off, 64);
        rv += __shfl_xor(rv, off, 64);
      }
      if (cc == 0) {
        al[(n0 + j) * 2 + head] = lv;
        ar[(n0 + j) * 2 + head] = rv;
      }
    }
    __syncthreads();  // previous iteration's packers done
#pragma unroll
    for (int j = 0; j < 4; j++) lds[j][c] = acc[j];
    __syncthreads();
#pragma unroll
    for (int r = 0; r < 2; r++) {
      int idx = c + r * 128;          // 0..255 -> (node j, channel cc)
      int j = idx >> 6, ccc = idx & 63;
      xl2h[(size_t)(n0 + j) * HID + ccc] =
          __floats2half2_rn(lds[j][ccc], lds[j][64 + ccc]);
    }
  }
}

// ---------------- per-layer edge aggregation ----------------
// 1 wave per dst node. Scores bounded (|e| <~ 2 — tanh-bounded inputs, glorot
// att vectors), so exp without max subtraction is numerically safe: single pass.
// Strip-parallel score compute, then serial readlane loop: per edge 3 readlanes
// + one coalesced 256B half2 gather + 2 FMA, 2x unrolled for MLP-in-flight.
// Edge-embedding term folded into per-head scalars (sum_p, sum_p*ea.{x,y}).
__global__ void k_aggregate(const __half2* __restrict__ xl2h, const float2* __restrict__ al2,
                            const float2* __restrict__ ar2, const int* __restrict__ start,
                            const int* __restrict__ degarr, const float4* __restrict__ erec,
                            const float* __restrict__ eW2, const float* __restrict__ eb1,
                            const float* __restrict__ bconv1, float* __restrict__ hout,
                            float* __restrict__ xmax, int first) {
  const int gid = blockIdx.x * 4 + (threadIdx.x >> 6);
  if (gid >= N_NODES) return;
  const int lane = threadIdx.x & 63;
  const int o0 = start[gid];
  const int deg = degarr[gid];
  const float2 arv = ar2[gid];

  float acc0 = 0.f, acc1 = 0.f;
  float ld0 = 0.f, ld1 = 0.f, lex0 = 0.f, ley0 = 0.f, lex1 = 0.f, ley1 = 0.f;
  for (int base = 0; base < deg; base += 64) {
    int j = base + lane;
    int s = 0; float p0 = 0.f, p1 = 0.f;
    if (j < deg) {
      float4 r = erec[o0 + j];
      s = __float_as_int(r.x);
      float2 alv = al2[s];
      p0 = __expf(lrelu(alv.x + arv.x));
      p1 = __expf(lrelu(alv.y + arv.y));
      ld0 += p0; ld1 += p1;
      lex0 += p0 * r.y; ley0 += p0 * r.z;
      lex1 += p1 * r.y; ley1 += p1 * r.z;
    }
    int slen = min(64, deg - base);
    int j2 = 0;
    for (; j2 + 2 <= slen; j2 += 2) {
      int   sA  = rli(s, j2),       sB  = rli(s, j2 + 1);
      float q0A = rlf(p0, j2),      q1A = rlf(p1, j2);
      float q0B = rlf(p0, j2 + 1),  q1B = rlf(p1, j2 + 1);
      float2 xA = __half22float2(xl2h[(size_t)sA * HID + lane]);
      float2 xB = __half22float2(xl2h[(size_t)sB * HID + lane]);
      acc0 += q0A * xA.x; acc1 += q1A * xA.y;
      acc0 += q0B * xB.x; acc1 += q1B * xB.y;
    }
    if (j2 < slen) {
      int   sA  = rli(s, j2);
      float q0A = rlf(p0, j2), q1A = rlf(p1, j2);
      float2 xA = __half22float2(xl2h[(size_t)sA * HID + lane]);
      acc0 += q0A * xA.x; acc1 += q1A * xA.y;
    }
  }
#pragma unroll
  for (int off = 32; off; off >>= 1) {
    ld0  += __shfl_xor(ld0, off, 64);
    ld1  += __shfl_xor(ld1, off, 64);
    lex0 += __shfl_xor(lex0, off, 64);
    ley0 += __shfl_xor(ley0, off, 64);
    lex1 += __shfl_xor(lex1, off, 64);
    ley1 += __shfl_xor(ley1, off, 64);
  }
  float t0 = acc0 + eW2[lane]      * lex0 + eW2[HC + lane]      * ley0 + eb1[lane]      * ld0;
  float t1 = acc1 + eW2[64 + lane] * lex1 + eW2[HC + 64 + lane] * ley1 + eb1[64 + lane] * ld1;
  float r = 0.5f * (t0 / (ld0 + 1e-16f) + t1 / (ld1 + 1e-16f)) + bconv1[lane];
  float hv = tanhf(r);
  hout[(size_t)gid * HID + lane] = hv;
  xmax[(size_t)gid * HID + lane] = first ? hv : fmaxf(xmax[(size_t)gid * HID + lane], hv);
}

// ---------------- fused pooling + MLP: one block per graph, no atomics ----------------
#define PF_LIST 512
#define PF_CAP  256
__global__ void k_pool_final(const float* __restrict__ xmax, const int* __restrict__ ipos,
                             const int* __restrict__ batch, const float* __restrict__ gate_w,
                             const float* __restrict__ gate_b, const float* __restrict__ lin1_w,
                             const float* __restrict__ lin1_b, const float* __restrict__ lin2_w,
                             const float* __restrict__ lin2_b, float* __restrict__ out) {
  __shared__ int   mnode[PF_LIST];
  __shared__ float gbuf[PF_LIST];
  __shared__ float rows[PF_CAP][HID];      // 64 KB row cache
  __shared__ float red[4][HID];
  __shared__ float red2[256];
  __shared__ float pooled[4 * HID];
  __shared__ float zred[2 * HID];
  __shared__ int   mcnt;
  __shared__ float sgmax, saden, swsc[4];

  const int g = blockIdx.x, t = threadIdx.x;
  const int w = t >> 6, lane = t & 63;
  const float gwv = gate_w[lane];

  // pass A: collect this graph's interface nodes
  if (t == 0) mcnt = 0;
  __syncthreads();
  for (int i = t; i < NI; i += 256) {
    int node = ipos[i];
    if (batch[node] == g) {
      int k = atomicAdd(&mcnt, 1);
      if (k < PF_LIST) mnode[k] = node;
    }
  }
  __syncthreads();
  const int cnt = min(mcnt, PF_LIST);

  // pass B: gate scores + add/max partials; cache rows in LDS
  float padd = 0.f, pmax = -1e30f;
  for (int m = w; m < cnt; m += 4) {
    int node = mnode[m];
    float v = xmax[(size_t)node * HID + lane];
    if (m < PF_CAP) rows[m][lane] = v;
    padd += v;
    pmax = fmaxf(pmax, v);
    float gv = v * gwv;
#pragma unroll
    for (int off = 32; off; off >>= 1) gv += __shfl_xor(gv, off, 64);
    if (lane == 0) gbuf[m] = gv + gate_b[0];
  }
  red[w][lane] = padd; __syncthreads();
  float addv = 0.f;
  if (w == 0) addv = red[0][lane] + red[1][lane] + red[2][lane] + red[3][lane];
  __syncthreads();
  red[w][lane] = pmax; __syncthreads();
  float maxv = 0.f;
  if (w == 0) maxv = fmaxf(fmaxf(red[0][lane], red[1][lane]), fmaxf(red[2][lane], red[3][lane]));
  __syncthreads();

  // gate max over this graph's nodes
  float lg = -1e30f;
  for (int m = t; m < cnt; m += 256) lg = fmaxf(lg, gbuf[m]);
  red2[t] = lg; __syncthreads();
  for (int off = 128; off; off >>= 1) { if (t < off) red2[t] = fmaxf(red2[t], red2[t + off]); __syncthreads(); }
  if (t == 0) sgmax = red2[0];
  __syncthreads();

  // pass C: attention-weighted sum
  float pattp = 0.f, paden = 0.f;
  for (int m = w; m < cnt; m += 4) {
    float a = __expf(gbuf[m] - sgmax);
    float v = (m < PF_CAP) ? rows[m][lane] : xmax[(size_t)mnode[m] * HID + lane];
    pattp += a * v;
    if (lane == 0) paden += a;
  }
  red[w][lane] = pattp;
  if (lane == 0) swsc[w] = paden;
  __syncthreads();
  if (t == 0) saden = swsc[0] + swsc[1] + swsc[2] + swsc[3];
  float attpv = 0.f;
  if (w == 0) attpv = red[0][lane] + red[1][lane] + red[2][lane] + red[3][lane];
  __syncthreads();

  if (w == 0) {
    float cntf = (float)mcnt;
    pooled[lane]       = addv;
    pooled[64 + lane]  = addv / fmaxf(cntf, 1.f);
    pooled[128 + lane] = attpv / (saden + 1e-16f);
    pooled[192 + lane] = maxv;
  }
  __syncthreads();

  // pass D: z = tanh(pooled @ lin1 + b1); out = z @ lin2 + b2
  if (t < 2 * HID) {
    float z = lin1_b[t];
    for (int k = 0; k < 4 * HID; k++) z += pooled[k] * lin1_w[k * (2 * HID) + t];
    zred[t] = tanhf(z) * lin2_w[t];
  }
  __syncthreads();
  if (t == 0) {
    float s = 0.f;
    for (int k = 0; k < 2 * HID; k++) s += zred[k];
    out[g] = s + lin2_b[0];
  }
}

extern "C" void kernel_launch(void* const* d_in, const int* in_sizes, int n_in,
                              void* d_out, int out_size, void* d_ws, size_t ws_size,
                              hipStream_t stream) {
  const float* x      = (const float*)d_in[0];
  const int*   ei     = (const int*)d_in[1];
  const float* eattr  = (const float*)d_in[2];
  const int*   batch  = (const int*)d_in[3];
  const int*   ipos   = (const int*)d_in[4];
  // d_in[5] = graph_num scalar (G=50, hardcoded)
  const float* W0     = (const float*)d_in[6];
  const float* attl0  = (const float*)d_in[7];
  const float* attr0  = (const float*)d_in[8];
  const float* W12    = (const float*)d_in[9];
  const float* attl12 = (const float*)d_in[10];
  const float* attr12 = (const float*)d_in[11];
  const float* eW     = (const float*)d_in[12];
  const float* eb     = (const float*)d_in[13];
  const float* bconv  = (const float*)d_in[14];
  const float* gate_w = (const float*)d_in[15];
  const float* gate_b = (const float*)d_in[16];
  const float* lin1_w = (const float*)d_in[17];
  const float* lin1_b = (const float*)d_in[18];
  const float* lin2_w = (const float*)d_in[19];
  const float* lin2_b = (const float*)d_in[20];
  float* out = (float*)d_out;

  char* ws = (char*)d_ws;
  size_t off = 0;
  auto alloc = [&](size_t elems) {
    void* p = ws + off;
    off += ((elems * 4 + 15) / 16) * 16;   // 16B-aligned slots
    return p;
  };
  // ---- zero-init region (contiguous, one memset) ----
  int* deg    = (int*)alloc(N_NODES);
  int* cursor = (int*)alloc(N_NODES);
  int* gcur   = (int*)alloc(4);
  size_t zbytes = off;
  // ---- rest ----
  int*     start = (int*)alloc(N_NODES);
  float*   erec  = (float*)alloc((size_t)NET * 4);
  __half2* xl2h  = (__half2*)alloc((size_t)N_NODES * HID);   // 4B each
  float*   al    = (float*)alloc((size_t)N_NODES * 2);
  float*   arr   = (float*)alloc((size_t)N_NODES * 2);
  float*   hbuf  = (float*)alloc((size_t)N_NODES * HID);
  float*   xmax  = (float*)alloc((size_t)N_NODES * HID);
  (void)ws_size; (void)in_sizes; (void)n_in; (void)out_size;

  hipMemsetAsync(d_ws, 0, zbytes, stream);
  k_hist<<<(NET + 255) / 256, 256, 0, stream>>>(ei, deg);
  k_base<<<(N_NODES + 255) / 256, 256, 0, stream>>>(deg, start, gcur);
  k_scatter<<<(NET + 255) / 256, 256, 0, stream>>>(ei, eattr, start, cursor, (float4*)erec);

  // layer 0
  k_linear<FIN><<<2500, 128, 0, stream>>>(x, W0, attl0, attr0, xl2h, al, arr);
  k_aggregate<<<N_NODES / 4, 256, 0, stream>>>(xl2h, (const float2*)al, (const float2*)arr,
                                               start, deg, (const float4*)erec,
                                               eW, eb, bconv, hbuf, xmax, 1);
  // layers 1,2
  for (int l = 0; l < 2; l++) {
    k_linear<HID><<<2500, 128, 0, stream>>>(hbuf, W12 + (size_t)l * HID * HC,
                                            attl12 + l * HC, attr12 + l * HC, xl2h, al, arr);
    k_aggregate<<<N_NODES / 4, 256, 0, stream>>>(xl2h, (const float2*)al, (const float2*)arr,
                                                 start, deg, (const float4*)erec,
                                                 eW + (l + 1) * 2 * HC, eb + (l + 1) * HC,
                                                 bconv + (l + 1) * HID, hbuf, xmax, 0);
  }

  k_pool_final<<<NG, 256, 0, stream>>>(xmax, ipos, batch, gate_w, gate_b,
                                       lin1_w, lin1_b, lin2_w, lin2_b, out);
}